// Round 4
// baseline (224.933 us; speedup 1.0000x reference)
//
#include <hip/hip_runtime.h>
#include <cstdint>
#include <cstddef>

// ---------------------------------------------------------------------------
// LSTM cell, B=8192, D=H=512, fp32 in/out.
// pre = [x|h] @ Wstack^T + bias ; gates -> c_t, h_t fused in GEMM epilogue.
// Round 4: B (weights) fragments loaded DIRECTLY global->VGPR (no LDS pass):
// halves LDS traffic and removes B from the barrier-drained staging path.
// A stays via global_load_lds. 128x128 tile, 256 thr, 4 waves of 64x64,
// grid (64,16) = 1024 blocks = 4/CU.
// ---------------------------------------------------------------------------

typedef __attribute__((ext_vector_type(8))) short short8;   // 8 bf16 = 4 VGPRs
typedef __attribute__((ext_vector_type(4))) float floatx4;  // MFMA acc

#define AS1(p) ((const __attribute__((address_space(1))) void*)(p))
#define AS3(p) ((__attribute__((address_space(3))) void*)(p))

__device__ __forceinline__ unsigned short f2bf(float f) {
  union { float f; unsigned u; } v; v.f = f;
  unsigned u = v.u;
  return (unsigned short)((u + 0x7fffu + ((u >> 16) & 1u)) >> 16);  // RNE
}

// --------------------------- pack everything -------------------------------
// blocks [0,8192):   A[b][k] = k<512 ? x[b][k] : h[b][k-512]      (8192x1024)
// blocks [8192,10240): B[n][k], n=gate*512+hh (f,i,g,o), k<512 -> Wx else Wh
//                      plus bias[n] = bx+bh at k==0.
struct PackArgs {
  const float* x; const float* h;
  const float* wx[4]; const float* wh[4];
  const float* bx[4]; const float* bh[4];
  unsigned short* A; unsigned short* B; float* bias;
};

__global__ __launch_bounds__(256) void pack_all_kernel(PackArgs P) {
  const int bid = blockIdx.x;
  if (bid < 8192) {
    int e = (bid * 256 + threadIdx.x) * 4;
    int b = e >> 10, k = e & 1023;
    const float* src = (k < 512) ? (P.x + b * 512 + k)
                                 : (P.h + b * 512 + (k - 512));
    float4 v = *(const float4*)src;
    ushort4 o;
    o.x = f2bf(v.x); o.y = f2bf(v.y); o.z = f2bf(v.z); o.w = f2bf(v.w);
    *(ushort4*)(P.A + e) = o;
  } else {
    int e = ((bid - 8192) * 256 + threadIdx.x) * 4;
    int n = e >> 10, k = e & 1023;
    int g = n >> 9, hh = n & 511;
    const float* src = (k < 512) ? (P.wx[g] + hh * 512 + k)
                                 : (P.wh[g] + hh * 512 + (k - 512));
    float4 v = *(const float4*)src;
    ushort4 o;
    o.x = f2bf(v.x); o.y = f2bf(v.y); o.z = f2bf(v.z); o.w = f2bf(v.w);
    *(ushort4*)(P.B + e) = o;
    if (k == 0) P.bias[n] = P.bx[g][hh] + P.bh[g][hh];
  }
}

// --------------------------- fused GEMM + LSTM epilogue --------------------
// Grid (64,16): tile = 128 batch x (4 gates x 32 hidden). K=1024, BK=64.
// 256 threads = 4 waves; wave tile 64x64 (4x4 frags of 16x16x32 bf16).
// A through LDS (16KB, XOR-swizzled); B fragments direct global->VGPR.
__global__ __launch_bounds__(256, 4)
void lstm_gemm_kernel(const unsigned short* __restrict__ A,   // [8192][1024]
                      const unsigned short* __restrict__ B,   // [2048][1024]
                      const float* __restrict__ bias,         // [2048]
                      const float* __restrict__ c_prev,       // [8192][512]
                      float* __restrict__ h_out,              // [8192][512]
                      float* __restrict__ c_out) {            // [8192][512]
  // A staging 16KB @ [0,16384); epilogue overlay float[64][132] = 33792 B
  __shared__ __align__(16) char smem[33792];
  __shared__ float biasS[128];

  const int tid  = threadIdx.x;
  const int lane = tid & 63;
  const int w    = tid >> 6;        // wave 0..3
  const int quad = lane >> 4;
  const int colA = lane & 15;
  const int m0   = blockIdx.x * 128;
  const int h0   = blockIdx.y * 32;

  if (tid < 128) {
    biasS[tid] = bias[(tid >> 5) * 512 + h0 + (tid & 31)];
  }

  // A staging: thread covers tile-row r = j*32 + (tid>>3), 16B chunk (tid&7);
  // global chunk XOR-swizzled by row&7 so ds_read_b128 frags are conflict-free
  const int srow = tid >> 3;        // 0..31
  const int cl   = tid & 7;
  const int cg   = cl ^ (srow & 7);

  floatx4 acc[4][4];
#pragma unroll
  for (int i = 0; i < 4; ++i)
#pragma unroll
    for (int j = 0; j < 4; ++j) acc[i][j] = (floatx4){0.f, 0.f, 0.f, 0.f};

  const int wm = (w >> 1) * 64;     // wave M offset in tile (0 or 64)
  const int wn = (w & 1) * 64;      // wave N' offset (N' = gate*32+h)

  const char* Ag = (const char*)A;

  // Per-wave B fragment base pointers (byte offsets), one per ni.
  // nn = wn + ni*16 + colA; global row = (nn>>5)*512 + h0 + (nn&31).
  const unsigned short* bp[4];
#pragma unroll
  for (int ni = 0; ni < 4; ++ni) {
    int nn = wn + ni * 16 + colA;
    int row = (nn >> 5) * 512 + h0 + (nn & 31);
    bp[ni] = B + (size_t)row * 1024 + quad * 8;   // + kk*32 + kt*64 later
  }

  for (int kt = 0; kt < 16; ++kt) {
    __syncthreads();                // prior iter's LDS reads done
    const int kb = kt * 128;        // byte offset into 2048-B rows
#pragma unroll
    for (int j = 0; j < 4; ++j) {   // A: 128 rows, 16KB
      int r = j * 32 + srow;
      __builtin_amdgcn_global_load_lds(
          AS1(Ag + (size_t)(m0 + r) * 2048 + kb + cg * 16),
          AS3(smem + r * 128 + cl * 16), 16, 0, 0);
    }
    __syncthreads();                // drains vmcnt(0)

#pragma unroll
    for (int kk = 0; kk < 2; ++kk) {
      const int off = ((kk * 4 + quad) ^ (colA & 7)) * 16;
      short8 af[4], bfr[4];
#pragma unroll
      for (int ni = 0; ni < 4; ++ni)
        bfr[ni] = *(const short8*)(bp[ni] + kt * 64 + kk * 32);
#pragma unroll
      for (int mi = 0; mi < 4; ++mi)
        af[mi] = *(const short8*)(smem + (wm + mi * 16 + colA) * 128 + off);
#pragma unroll
      for (int mi = 0; mi < 4; ++mi)
#pragma unroll
        for (int ni = 0; ni < 4; ++ni)
          acc[mi][ni] = __builtin_amdgcn_mfma_f32_16x16x32_bf16(
              af[mi], bfr[ni], acc[mi][ni], 0, 0, 0);
    }
  }

  // ------------------- fused epilogue (2 rounds of 64 M-rows) --------------
  __syncthreads();
  float* ep = (float*)smem;         // [64][132] padded, overlays A staging
#pragma unroll
  for (int rd = 0; rd < 2; ++rd) {
    if ((w >> 1) == rd) {           // the 2 waves with wm == rd*64
      // C/D layout: row = quad*4 + rr, col = lane&15
#pragma unroll
      for (int mi = 0; mi < 4; ++mi)
#pragma unroll
        for (int ni = 0; ni < 4; ++ni) {
          int rr0 = mi * 16 + quad * 4;                 // 0..63
          int cc  = wn + ni * 16 + colA;                // 0..127
#pragma unroll
          for (int rr = 0; rr < 4; ++rr)
            ep[(rr0 + rr) * 132 + cc] = acc[mi][ni][rr];
        }
    }
    __syncthreads();
#pragma unroll
    for (int j = 0; j < 8; ++j) {
      int idx  = j * 256 + tid;     // 0..2047
      int mloc = idx >> 5;
      int hh   = idx & 31;
      float pf = ep[mloc * 132 +      hh] + biasS[hh];
      float pi = ep[mloc * 132 + 32 + hh] + biasS[32 + hh];
      float pg = ep[mloc * 132 + 64 + hh] + biasS[64 + hh];
      float po = ep[mloc * 132 + 96 + hh] + biasS[96 + hh];
      float fg = 1.f / (1.f + __expf(-pf));
      float ig = 1.f / (1.f + __expf(-pi));
      float gg = 1.f - 2.f / (1.f + __expf(2.f * pg));
      float og = 1.f / (1.f + __expf(-po));
      int m  = m0 + rd * 64 + mloc;
      int hg = h0 + hh;
      float cp = c_prev[m * 512 + hg];
      float cv = fg * cp + ig * gg;
      float th = 1.f - 2.f / (1.f + __expf(2.f * cv));
      h_out[m * 512 + hg] = og * th;
      c_out[m * 512 + hg] = cv;
    }
    __syncthreads();
  }
}

// ---------------------------------------------------------------------------
extern "C" void kernel_launch(void* const* d_in, const int* in_sizes, int n_in,
                              void* d_out, int out_size, void* d_ws, size_t ws_size,
                              hipStream_t stream) {
  // workspace: A_bf16 (16 MiB) | B_bf16 (4 MiB) | bias (8 KiB)
  char* ws = (char*)d_ws;
  unsigned short* Abf = (unsigned short*)ws;
  unsigned short* Bbf = (unsigned short*)(ws + (size_t)16777216);
  float* bias = (float*)(ws + (size_t)16777216 + 4194304);

  float* hout = (float*)d_out;
  float* cout = hout + (size_t)8192 * 512;

  PackArgs P;
  P.x = (const float*)d_in[0];
  P.h = (const float*)d_in[1];
  // gate order in stacked B: 0=f, 1=i, 2=g(cell), 3=o
  P.wx[0] = (const float*)d_in[3];  P.bx[0] = (const float*)d_in[4];
  P.wh[0] = (const float*)d_in[5];  P.bh[0] = (const float*)d_in[6];
  P.wx[1] = (const float*)d_in[7];  P.bx[1] = (const float*)d_in[8];
  P.wh[1] = (const float*)d_in[9];  P.bh[1] = (const float*)d_in[10];
  P.wx[2] = (const float*)d_in[11]; P.bx[2] = (const float*)d_in[12];
  P.wh[2] = (const float*)d_in[13]; P.bh[2] = (const float*)d_in[14];
  P.wx[3] = (const float*)d_in[15]; P.bx[3] = (const float*)d_in[16];
  P.wh[3] = (const float*)d_in[17]; P.bh[3] = (const float*)d_in[18];
  P.A = Abf; P.B = Bbf; P.bias = bias;

  pack_all_kernel<<<10240, 256, 0, stream>>>(P);

  const float* c = (const float*)d_in[2];
  dim3 grid(64, 16);
  lstm_gemm_kernel<<<grid, 256, 0, stream>>>(Abf, Bbf, bias, c, hout, cout);
}

// Round 5
// 177.411 us; speedup vs baseline: 1.2679x; 1.2679x over previous
//
#include <hip/hip_runtime.h>
#include <cstdint>
#include <cstddef>

// ---------------------------------------------------------------------------
// LSTM cell, B=8192, D=H=512, fp32 in/out.
// pre = [x|h] @ Wstack^T + bias ; gates -> c_t, h_t fused in GEMM epilogue.
// Round 5: 256x256 tile, 1 block/CU (grid 32x8), 8 waves of 128x64 to cut
// LDS read duplication; DOUBLE-BUFFERED A+B staging (4 x 32KB LDS) with loads
// issued BEFORE compute so the per-kt barrier drain overlaps MFMA.
// B back through LDS (round 4's B-direct spilled: WRITE_SIZE +20MB scratch).
// ---------------------------------------------------------------------------

typedef __attribute__((ext_vector_type(8))) short short8;   // 8 bf16 = 4 VGPRs
typedef __attribute__((ext_vector_type(4))) float floatx4;  // MFMA acc

#define AS1(p) ((const __attribute__((address_space(1))) void*)(p))
#define AS3(p) ((__attribute__((address_space(3))) void*)(p))

__device__ __forceinline__ unsigned short f2bf(float f) {
  union { float f; unsigned u; } v; v.f = f;
  unsigned u = v.u;
  return (unsigned short)((u + 0x7fffu + ((u >> 16) & 1u)) >> 16);  // RNE
}

// --------------------------- pack everything -------------------------------
// blocks [0,8192):   A[b][k] = k<512 ? x[b][k] : h[b][k-512]      (8192x1024)
// blocks [8192,10240): B[n][k], n=gate*512+hh (f,i,g,o), k<512 -> Wx else Wh
//                      plus bias[n] = bx+bh at k==0.
struct PackArgs {
  const float* x; const float* h;
  const float* wx[4]; const float* wh[4];
  const float* bx[4]; const float* bh[4];
  unsigned short* A; unsigned short* B; float* bias;
};

__global__ __launch_bounds__(256) void pack_all_kernel(PackArgs P) {
  const int bid = blockIdx.x;
  if (bid < 8192) {
    int e = (bid * 256 + threadIdx.x) * 4;
    int b = e >> 10, k = e & 1023;
    const float* src = (k < 512) ? (P.x + b * 512 + k)
                                 : (P.h + b * 512 + (k - 512));
    float4 v = *(const float4*)src;
    ushort4 o;
    o.x = f2bf(v.x); o.y = f2bf(v.y); o.z = f2bf(v.z); o.w = f2bf(v.w);
    *(ushort4*)(P.A + e) = o;
  } else {
    int e = ((bid - 8192) * 256 + threadIdx.x) * 4;
    int n = e >> 10, k = e & 1023;
    int g = n >> 9, hh = n & 511;
    const float* src = (k < 512) ? (P.wx[g] + hh * 512 + k)
                                 : (P.wh[g] + hh * 512 + (k - 512));
    float4 v = *(const float4*)src;
    ushort4 o;
    o.x = f2bf(v.x); o.y = f2bf(v.y); o.z = f2bf(v.z); o.w = f2bf(v.w);
    *(ushort4*)(P.B + e) = o;
    if (k == 0) P.bias[n] = P.bx[g][hh] + P.bh[g][hh];
  }
}

// --------------------------- fused GEMM + LSTM epilogue --------------------
// Grid (32,8): tile = 256 batch x (4 gates x 64 hidden). K=1024, BK=64.
// 512 threads = 8 waves (2 wm x 4 wn); wave tile 128x64 (8x4 frags 16x16x32).
// LDS: A dbuf 2x32KB @ [0,64K), B dbuf 2x32KB @ [64K,128K); ep overlays.
__global__ __launch_bounds__(512, 2)
void lstm_gemm_kernel(const unsigned short* __restrict__ A,   // [8192][1024]
                      const unsigned short* __restrict__ B,   // [2048][1024]
                      const float* __restrict__ bias,         // [2048]
                      const float* __restrict__ c_prev,       // [8192][512]
                      float* __restrict__ h_out,              // [8192][512]
                      float* __restrict__ c_out) {            // [8192][512]
  __shared__ __align__(16) char smem[131072];
  __shared__ float biasS[256];

  const int tid  = threadIdx.x;
  const int lane = tid & 63;
  const int w    = tid >> 6;        // wave 0..7
  const int quad = lane >> 4;
  const int colA = lane & 15;
  const int m0   = blockIdx.x * 256;
  const int h0   = blockIdx.y * 64;

  if (tid < 256) {
    // ep-col c -> gate c>>6, hidden h0 + (c&63)
    biasS[tid] = bias[(tid >> 6) * 512 + h0 + (tid & 63)];
  }

  // staging: thread covers tile-row r = j*64 + (tid>>3), 16B chunk (tid&7);
  // global chunk XOR-swizzled by row&7 -> conflict-free ds_read_b128 frags.
  const int srow = tid >> 3;        // 0..63
  const int cl   = tid & 7;
  const int cg   = cl ^ (srow & 7);

  floatx4 acc[8][4];
#pragma unroll
  for (int i = 0; i < 8; ++i)
#pragma unroll
    for (int j = 0; j < 4; ++j) acc[i][j] = (floatx4){0.f, 0.f, 0.f, 0.f};

  const int wm = (w >> 2) * 128;    // wave M offset (0 or 128)
  const int wn = (w & 3) * 64;      // wave N' offset (0,64,128,192)

  const char* Ag = (const char*)A;
  const char* Bg = (const char*)B;

  // ---- stage kt=0 into buffer 0 ----
#pragma unroll
  for (int j = 0; j < 4; ++j) {
    int r = j * 64 + srow;
    __builtin_amdgcn_global_load_lds(
        AS1(Ag + (size_t)(m0 + r) * 2048 + cg * 16),
        AS3(smem + r * 128 + cl * 16), 16, 0, 0);
    int grow = (r >> 6) * 512 + h0 + (r & 63);
    __builtin_amdgcn_global_load_lds(
        AS1(Bg + (size_t)grow * 2048 + cg * 16),
        AS3(smem + 65536 + r * 128 + cl * 16), 16, 0, 0);
  }
  __syncthreads();

  for (int kt = 0; kt < 16; ++kt) {
    const int cur = kt & 1;
    // ---- issue next tile's staging FIRST (overlaps with compute below) ----
    if (kt < 15) {
      const int nb = cur ^ 1;
      const int kb = (kt + 1) * 128;
#pragma unroll
      for (int j = 0; j < 4; ++j) {
        int r = j * 64 + srow;
        __builtin_amdgcn_global_load_lds(
            AS1(Ag + (size_t)(m0 + r) * 2048 + kb + cg * 16),
            AS3(smem + nb * 32768 + r * 128 + cl * 16), 16, 0, 0);
        int grow = (r >> 6) * 512 + h0 + (r & 63);
        __builtin_amdgcn_global_load_lds(
            AS1(Bg + (size_t)grow * 2048 + kb + cg * 16),
            AS3(smem + 65536 + nb * 32768 + r * 128 + cl * 16), 16, 0, 0);
      }
    }
    // ---- compute on current buffer ----
    const char* Ab = smem + cur * 32768;
    const char* Bb = smem + 65536 + cur * 32768;
#pragma unroll
    for (int kk = 0; kk < 2; ++kk) {
      const int off = ((kk * 4 + quad) ^ (colA & 7)) * 16;
      short8 af[8], bfr[4];
#pragma unroll
      for (int ni = 0; ni < 4; ++ni)
        bfr[ni] = *(const short8*)(Bb + (wn + ni * 16 + colA) * 128 + off);
#pragma unroll
      for (int mi = 0; mi < 8; ++mi)
        af[mi] = *(const short8*)(Ab + (wm + mi * 16 + colA) * 128 + off);
#pragma unroll
      for (int mi = 0; mi < 8; ++mi)
#pragma unroll
        for (int ni = 0; ni < 4; ++ni)
          acc[mi][ni] = __builtin_amdgcn_mfma_f32_16x16x32_bf16(
              af[mi], bfr[ni], acc[mi][ni], 0, 0, 0);
    }
    __syncthreads();   // drains vmcnt(0): next-tile loads had compute to fly
  }

  // ------------------- fused epilogue (4 rounds of 64 M-rows) --------------
  float* ep = (float*)smem;         // [64][260] padded, overlays staging
#pragma unroll
  for (int rd = 0; rd < 4; ++rd) {
    if ((w >> 2) == (rd >> 1)) {    // 4 waves own these 128 M-rows
      const int sub = (rd & 1) * 4; // mi base within the wave
      // C/D layout: row = quad*4 + rr, col = lane&15
#pragma unroll
      for (int mi2 = 0; mi2 < 4; ++mi2)
#pragma unroll
        for (int ni = 0; ni < 4; ++ni) {
          int rr0 = mi2 * 16 + quad * 4;                // 0..63
          int cc  = wn + ni * 16 + colA;                // 0..255
#pragma unroll
          for (int rr = 0; rr < 4; ++rr)
            ep[(rr0 + rr) * 260 + cc] = acc[sub + mi2][ni][rr];
        }
    }
    __syncthreads();
#pragma unroll
    for (int j = 0; j < 8; ++j) {
      int idx  = j * 512 + tid;     // 0..4095
      int mloc = idx >> 6;
      int hh   = idx & 63;
      float pf = ep[mloc * 260 +       hh] + biasS[hh];
      float pi = ep[mloc * 260 +  64 + hh] + biasS[64 + hh];
      float pg = ep[mloc * 260 + 128 + hh] + biasS[128 + hh];
      float po = ep[mloc * 260 + 192 + hh] + biasS[192 + hh];
      float fg = 1.f / (1.f + __expf(-pf));
      float ig = 1.f / (1.f + __expf(-pi));
      float gg = 1.f - 2.f / (1.f + __expf(2.f * pg));
      float og = 1.f / (1.f + __expf(-po));
      int m  = m0 + rd * 64 + mloc;
      int hg = h0 + hh;
      float cp = c_prev[m * 512 + hg];
      float cv = fg * cp + ig * gg;
      float th = 1.f - 2.f / (1.f + __expf(2.f * cv));
      h_out[m * 512 + hg] = og * th;
      c_out[m * 512 + hg] = cv;
    }
    __syncthreads();
  }
}

// ---------------------------------------------------------------------------
extern "C" void kernel_launch(void* const* d_in, const int* in_sizes, int n_in,
                              void* d_out, int out_size, void* d_ws, size_t ws_size,
                              hipStream_t stream) {
  // workspace: A_bf16 (16 MiB) | B_bf16 (4 MiB) | bias (8 KiB)
  char* ws = (char*)d_ws;
  unsigned short* Abf = (unsigned short*)ws;
  unsigned short* Bbf = (unsigned short*)(ws + (size_t)16777216);
  float* bias = (float*)(ws + (size_t)16777216 + 4194304);

  float* hout = (float*)d_out;
  float* cout = hout + (size_t)8192 * 512;

  PackArgs P;
  P.x = (const float*)d_in[0];
  P.h = (const float*)d_in[1];
  // gate order in stacked B: 0=f, 1=i, 2=g(cell), 3=o
  P.wx[0] = (const float*)d_in[3];  P.bx[0] = (const float*)d_in[4];
  P.wh[0] = (const float*)d_in[5];  P.bh[0] = (const float*)d_in[6];
  P.wx[1] = (const float*)d_in[7];  P.bx[1] = (const float*)d_in[8];
  P.wh[1] = (const float*)d_in[9];  P.bh[1] = (const float*)d_in[10];
  P.wx[2] = (const float*)d_in[11]; P.bx[2] = (const float*)d_in[12];
  P.wh[2] = (const float*)d_in[13]; P.bh[2] = (const float*)d_in[14];
  P.wx[3] = (const float*)d_in[15]; P.bx[3] = (const float*)d_in[16];
  P.wh[3] = (const float*)d_in[17]; P.bh[3] = (const float*)d_in[18];
  P.A = Abf; P.B = Bbf; P.bias = bias;

  pack_all_kernel<<<10240, 256, 0, stream>>>(P);

  const float* c = (const float*)d_in[2];
  dim3 grid(32, 8);
  lstm_gemm_kernel<<<grid, 512, 0, stream>>>(Abf, Bbf, bias, c, hout, cout);
}

// Round 6
// 173.656 us; speedup vs baseline: 1.2953x; 1.0216x over previous
//
#include <hip/hip_runtime.h>
#include <cstdint>
#include <cstddef>

// ---------------------------------------------------------------------------
// LSTM cell, B=8192, D=H=512, fp32 in/out.
// pre = [x|h] @ Wstack^T + bias ; gates -> c_t, h_t fused in GEMM epilogue.
// Round 6: the untested quadrant — 2 blocks/CU AND double-buffering.
// 128x128 tile, 256 thr, 4 waves of 64x64, dbuf A+B = 64 KB LDS ->
// 2 resident blocks/CU (two independent barrier domains, anti-phased drains),
// staging for kt+1 issued before compute on kt (a full compute-phase of
// flight time). R5 showed dbuf at 1 block/CU starves the CU at each barrier;
// R3 showed 2 blocks/CU serializes without dbuf. This combines both fixes.
// ---------------------------------------------------------------------------

typedef __attribute__((ext_vector_type(8))) short short8;   // 8 bf16 = 4 VGPRs
typedef __attribute__((ext_vector_type(4))) float floatx4;  // MFMA acc

#define AS1(p) ((const __attribute__((address_space(1))) void*)(p))
#define AS3(p) ((__attribute__((address_space(3))) void*)(p))

__device__ __forceinline__ unsigned short f2bf(float f) {
  union { float f; unsigned u; } v; v.f = f;
  unsigned u = v.u;
  return (unsigned short)((u + 0x7fffu + ((u >> 16) & 1u)) >> 16);  // RNE
}

// --------------------------- pack everything -------------------------------
// blocks [0,8192):   A[b][k] = k<512 ? x[b][k] : h[b][k-512]      (8192x1024)
// blocks [8192,10240): B[n][k], n=gate*512+hh (f,i,g,o), k<512 -> Wx else Wh
//                      plus bias[n] = bx+bh at k==0.
struct PackArgs {
  const float* x; const float* h;
  const float* wx[4]; const float* wh[4];
  const float* bx[4]; const float* bh[4];
  unsigned short* A; unsigned short* B; float* bias;
};

__global__ __launch_bounds__(256) void pack_all_kernel(PackArgs P) {
  const int bid = blockIdx.x;
  if (bid < 8192) {
    int e = (bid * 256 + threadIdx.x) * 4;
    int b = e >> 10, k = e & 1023;
    const float* src = (k < 512) ? (P.x + b * 512 + k)
                                 : (P.h + b * 512 + (k - 512));
    float4 v = *(const float4*)src;
    ushort4 o;
    o.x = f2bf(v.x); o.y = f2bf(v.y); o.z = f2bf(v.z); o.w = f2bf(v.w);
    *(ushort4*)(P.A + e) = o;
  } else {
    int e = ((bid - 8192) * 256 + threadIdx.x) * 4;
    int n = e >> 10, k = e & 1023;
    int g = n >> 9, hh = n & 511;
    const float* src = (k < 512) ? (P.wx[g] + hh * 512 + k)
                                 : (P.wh[g] + hh * 512 + (k - 512));
    float4 v = *(const float4*)src;
    ushort4 o;
    o.x = f2bf(v.x); o.y = f2bf(v.y); o.z = f2bf(v.z); o.w = f2bf(v.w);
    *(ushort4*)(P.B + e) = o;
    if (k == 0) P.bias[n] = P.bx[g][hh] + P.bh[g][hh];
  }
}

// --------------------------- fused GEMM + LSTM epilogue --------------------
// Grid (64,16): tile = 128 batch x (4 gates x 32 hidden). K=1024, BK=64.
// 256 threads = 4 waves; wave tile 64x64 (4x4 frags of 16x16x32 bf16).
// LDS: buffer b at [b*32768, b*32768+32768): A 16KB then B 16KB. 64 KB total
// -> 2 resident blocks/CU. Epilogue overlays buffer 0 (33792 B < 64 KB).
__global__ __launch_bounds__(256, 2)
void lstm_gemm_kernel(const unsigned short* __restrict__ A,   // [8192][1024]
                      const unsigned short* __restrict__ B,   // [2048][1024]
                      const float* __restrict__ bias,         // [2048]
                      const float* __restrict__ c_prev,       // [8192][512]
                      float* __restrict__ h_out,              // [8192][512]
                      float* __restrict__ c_out) {            // [8192][512]
  __shared__ __align__(16) char smem[65536];
  __shared__ float biasS[128];

  const int tid  = threadIdx.x;
  const int lane = tid & 63;
  const int w    = tid >> 6;        // wave 0..3
  const int quad = lane >> 4;
  const int colA = lane & 15;
  const int m0   = blockIdx.x * 128;
  const int h0   = blockIdx.y * 32;

  if (tid < 128) {
    biasS[tid] = bias[(tid >> 5) * 512 + h0 + (tid & 31)];
  }

  // staging: thread covers tile-row r = j*32 + (tid>>3), 16B chunk (tid&7);
  // global chunk XOR-swizzled by row&7 -> conflict-free ds_read_b128 frags.
  const int srow = tid >> 3;        // 0..31
  const int cl   = tid & 7;
  const int cg   = cl ^ (srow & 7);

  floatx4 acc[4][4];
#pragma unroll
  for (int i = 0; i < 4; ++i)
#pragma unroll
    for (int j = 0; j < 4; ++j) acc[i][j] = (floatx4){0.f, 0.f, 0.f, 0.f};

  const int wm = (w >> 1) * 64;     // wave M offset (0 or 64)
  const int wn = (w & 1) * 64;      // wave N' offset (0 or 64)

  const char* Ag = (const char*)A;
  const char* Bg = (const char*)B;

  // ---- stage kt=0 into buffer 0 ----
#pragma unroll
  for (int j = 0; j < 4; ++j) {
    int r = j * 32 + srow;          // 0..127
    __builtin_amdgcn_global_load_lds(
        AS1(Ag + (size_t)(m0 + r) * 2048 + cg * 16),
        AS3(smem + r * 128 + cl * 16), 16, 0, 0);
    int grow = (r >> 5) * 512 + h0 + (r & 31);
    __builtin_amdgcn_global_load_lds(
        AS1(Bg + (size_t)grow * 2048 + cg * 16),
        AS3(smem + 16384 + r * 128 + cl * 16), 16, 0, 0);
  }
  __syncthreads();

  for (int kt = 0; kt < 16; ++kt) {
    const int cur = kt & 1;
    // ---- issue next tile's staging first (flies during compute below) ----
    if (kt < 15) {
      const int nb = cur ^ 1;
      const int kb = (kt + 1) * 128;
      char* sb = smem + nb * 32768;
#pragma unroll
      for (int j = 0; j < 4; ++j) {
        int r = j * 32 + srow;
        __builtin_amdgcn_global_load_lds(
            AS1(Ag + (size_t)(m0 + r) * 2048 + kb + cg * 16),
            AS3(sb + r * 128 + cl * 16), 16, 0, 0);
        int grow = (r >> 5) * 512 + h0 + (r & 31);
        __builtin_amdgcn_global_load_lds(
            AS1(Bg + (size_t)grow * 2048 + kb + cg * 16),
            AS3(sb + 16384 + r * 128 + cl * 16), 16, 0, 0);
      }
    }
    // ---- compute on current buffer ----
    const char* Ab = smem + cur * 32768;
    const char* Bb = Ab + 16384;
#pragma unroll
    for (int kk = 0; kk < 2; ++kk) {
      const int off = ((kk * 4 + quad) ^ (colA & 7)) * 16;
      short8 af[4], bfr[4];
#pragma unroll
      for (int mi = 0; mi < 4; ++mi)
        af[mi] = *(const short8*)(Ab + (wm + mi * 16 + colA) * 128 + off);
#pragma unroll
      for (int ni = 0; ni < 4; ++ni)
        bfr[ni] = *(const short8*)(Bb + (wn + ni * 16 + colA) * 128 + off);
#pragma unroll
      for (int mi = 0; mi < 4; ++mi)
#pragma unroll
        for (int ni = 0; ni < 4; ++ni)
          acc[mi][ni] = __builtin_amdgcn_mfma_f32_16x16x32_bf16(
              af[mi], bfr[ni], acc[mi][ni], 0, 0, 0);
    }
    __syncthreads();   // drain: next-tile loads had a full compute phase
  }

  // ------------------- fused epilogue (2 rounds of 64 M-rows) --------------
  float* ep = (float*)smem;         // [64][132] padded, overlays buffer 0
#pragma unroll
  for (int rd = 0; rd < 2; ++rd) {
    if ((w >> 1) == rd) {           // the 2 waves with wm == rd*64
      // C/D layout: row = quad*4 + rr, col = lane&15
#pragma unroll
      for (int mi = 0; mi < 4; ++mi)
#pragma unroll
        for (int ni = 0; ni < 4; ++ni) {
          int rr0 = mi * 16 + quad * 4;                 // 0..63
          int cc  = wn + ni * 16 + colA;                // 0..127
#pragma unroll
          for (int rr = 0; rr < 4; ++rr)
            ep[(rr0 + rr) * 132 + cc] = acc[mi][ni][rr];
        }
    }
    __syncthreads();
#pragma unroll
    for (int j = 0; j < 8; ++j) {
      int idx  = j * 256 + tid;     // 0..2047
      int mloc = idx >> 5;
      int hh   = idx & 31;
      float pf = ep[mloc * 132 +      hh] + biasS[hh];
      float pi = ep[mloc * 132 + 32 + hh] + biasS[32 + hh];
      float pg = ep[mloc * 132 + 64 + hh] + biasS[64 + hh];
      float po = ep[mloc * 132 + 96 + hh] + biasS[96 + hh];
      float fg = 1.f / (1.f + __expf(-pf));
      float ig = 1.f / (1.f + __expf(-pi));
      float gg = 1.f - 2.f / (1.f + __expf(2.f * pg));
      float og = 1.f / (1.f + __expf(-po));
      int m  = m0 + rd * 64 + mloc;
      int hg = h0 + hh;
      float cp = c_prev[m * 512 + hg];
      float cv = fg * cp + ig * gg;
      float th = 1.f - 2.f / (1.f + __expf(2.f * cv));
      h_out[m * 512 + hg] = og * th;
      c_out[m * 512 + hg] = cv;
    }
    __syncthreads();
  }
}

// ---------------------------------------------------------------------------
extern "C" void kernel_launch(void* const* d_in, const int* in_sizes, int n_in,
                              void* d_out, int out_size, void* d_ws, size_t ws_size,
                              hipStream_t stream) {
  // workspace: A_bf16 (16 MiB) | B_bf16 (4 MiB) | bias (8 KiB)
  char* ws = (char*)d_ws;
  unsigned short* Abf = (unsigned short*)ws;
  unsigned short* Bbf = (unsigned short*)(ws + (size_t)16777216);
  float* bias = (float*)(ws + (size_t)16777216 + 4194304);

  float* hout = (float*)d_out;
  float* cout = hout + (size_t)8192 * 512;

  PackArgs P;
  P.x = (const float*)d_in[0];
  P.h = (const float*)d_in[1];
  // gate order in stacked B: 0=f, 1=i, 2=g(cell), 3=o
  P.wx[0] = (const float*)d_in[3];  P.bx[0] = (const float*)d_in[4];
  P.wh[0] = (const float*)d_in[5];  P.bh[0] = (const float*)d_in[6];
  P.wx[1] = (const float*)d_in[7];  P.bx[1] = (const float*)d_in[8];
  P.wh[1] = (const float*)d_in[9];  P.bh[1] = (const float*)d_in[10];
  P.wx[2] = (const float*)d_in[11]; P.bx[2] = (const float*)d_in[12];
  P.wh[2] = (const float*)d_in[13]; P.bh[2] = (const float*)d_in[14];
  P.wx[3] = (const float*)d_in[15]; P.bx[3] = (const float*)d_in[16];
  P.wh[3] = (const float*)d_in[17]; P.bh[3] = (const float*)d_in[18];
  P.A = Abf; P.B = Bbf; P.bias = bias;

  pack_all_kernel<<<10240, 256, 0, stream>>>(P);

  const float* c = (const float*)d_in[2];
  dim3 grid(64, 16);
  lstm_gemm_kernel<<<grid, 256, 0, stream>>>(Abf, Bbf, bias, c, hout, cout);
}